// Round 6
// baseline (124.839 us; speedup 1.0000x reference)
//
#include <hip/hip_runtime.h>

// Viterbi trellis quantizer: S=1024 states, K=2 (4 predecessors), CHUNK=4,
// block_size=16 -> T=64 steps/chain, B=4096 chains (16x16 blocks of 1024^2).
//
// beta-formulation: beta_t[s] = M_{t-1}[s>>2] + (cb[s]·x_t + h[s]),
//   h = -||cb||^2/2, M_t[p] = max_j beta_t[p + 256j], M_{-1} = 0.
//
// R8. Evidence: R7 (1 chain/block, VGPR 32, occ 66%) = 63us ~= R3 (57.5us):
// residency is NOT the constraint. Step wall ~1200cyc vs ~528cyc aggregate
// issue from 8 waves/SIMD -> ~55% of each step is the uncovered serial hole
// (M write -> barrier -> M read -> short fma/max chain), and all waves hit
// it in phase. Fix: amortize the hole with MORE ISSUE WORK PER BARRIER.
//  1. TWO chains per 256-thread block; both updated between barriers
//     (per-wave issue per step 66 -> 132 cyc against the same stall).
//  2. Ballot-packed backpointers: 2-bit j gathered via 2x __ballot, lane 0
//     writes one ulonglong2 per wave -> J LDS 15.75KB -> 4KB per chain;
//     block total ~14.8KB -> 8 blocks/CU resident.
//  3. waves_per_eu(8,8): hard 64-VGPR budget (demand ~58) so 32 waves/CU.
// Decisions bit-identical to R7 (same fmaf chains, same tie-breaks).
// Tripwires: VGPR_Count > 64 (budget missed), WRITE_SIZE > 5120 KB (spill).

#define COLS      1024
#define T_STEPS   64
#define REC_SIZE  (1024 * 1024)

__global__ __launch_bounds__(256)
__attribute__((amdgpu_waves_per_eu(8, 8)))
void viterbi_q(
    const float* __restrict__ arr,
    const float* __restrict__ cbook,
    float* __restrict__ out)
{
    const int tid  = threadIdx.x;        // owns trellis group p = tid, both chains
    const int lane = tid & 63;
    const int wid  = tid >> 6;

    __shared__ __align__(16) float tile[2][256];      // [ch] x chunks
    __shared__ __align__(16) float Mb[2][2][256];     // [ch][pingpong] grouped max
    __shared__ __align__(16) ulonglong2 J64[2][63 * 4]; // [ch][(t<<2)|wave] packed j
    __shared__ int   st_lds[2][64];                   // [ch] traced-back states
    __shared__ float redv[2][4];                      // [ch][wave] argmax scratch
    __shared__ int   reds[2][4];

    // ---- stage both 16x16 tiles into LDS (tile[ch][e], e = r*16 + c) ----
    if (tid < 128) {
        const int ch    = tid >> 6;
        const int e     = tid & 63;
        const int chain = (blockIdx.x << 1) | ch;
        const int rb    = chain >> 6, cb = chain & 63;
        const int r  = e >> 2;
        const int c4 = (e & 3) << 2;
        float4 v = *(const float4*)(arr + (rb * 16 + r) * COLS + cb * 16 + c4);
        *(float4*)&tile[ch][e << 2] = v;
    }
    Mb[0][0][tid] = 0.f;   // M_{-1} = 0: step 0 computes beta0 = cb·x0 + h
    Mb[1][0][tid] = 0.f;

    // ---- codebook rows for this thread's 4 states: s = tid + 256j ----
    // (shared by both chains)
    float4 a[4];
    float  h[4];
    #pragma unroll
    for (int j = 0; j < 4; ++j) {
        float4 v = *(const float4*)(cbook + (tid + (j << 8)) * 4);
        a[j] = v;
        h[j] = -0.5f * (v.x * v.x + v.y * v.y + v.z * v.z + v.w * v.w);
    }

    __syncthreads();

    // one trellis step for BOTH chains; read Mb[ch][RB], write Mb[ch][WB].
    // candidates ascend in j -> first-max = reference first-min over alpha.
#define STEP2(T, RB, WB)                                                      \
    {                                                                         \
        const float4 xtA = *(const float4*)&tile[0][(T) << 2];                \
        const float4 xtB = *(const float4*)&tile[1][(T) << 2];                \
        float mjA[4], mjB[4];                                                 \
        _Pragma("unroll")                                                     \
        for (int j = 0; j < 4; ++j) mjA[j] = Mb[0][RB][(tid >> 2) + (j << 6)];\
        _Pragma("unroll")                                                     \
        for (int j = 0; j < 4; ++j) mjB[j] = Mb[1][RB][(tid >> 2) + (j << 6)];\
        float candA[4], candB[4];                                             \
        _Pragma("unroll")                                                     \
        for (int j = 0; j < 4; ++j) {                                         \
            float acc = fmaf(a[j].x, xtA.x, h[j]);                            \
            acc = fmaf(a[j].y, xtA.y, acc);                                   \
            acc = fmaf(a[j].z, xtA.z, acc);                                   \
            acc = fmaf(a[j].w, xtA.w, acc);                                   \
            candA[j] = acc + mjA[j];                                          \
        }                                                                     \
        _Pragma("unroll")                                                     \
        for (int j = 0; j < 4; ++j) {                                         \
            float acc = fmaf(a[j].x, xtB.x, h[j]);                            \
            acc = fmaf(a[j].y, xtB.y, acc);                                   \
            acc = fmaf(a[j].z, xtB.z, acc);                                   \
            acc = fmaf(a[j].w, xtB.w, acc);                                   \
            candB[j] = acc + mjB[j];                                          \
        }                                                                     \
        const float vA = fmaxf(fmaxf(fmaxf(candA[0], candA[1]), candA[2]),    \
                               candA[3]);                                     \
        const int jA = (candA[0] == vA) ? 0                                   \
                     : (candA[1] == vA) ? 1                                   \
                     : (candA[2] == vA) ? 2 : 3;                              \
        const float vB = fmaxf(fmaxf(fmaxf(candB[0], candB[1]), candB[2]),    \
                               candB[3]);                                     \
        const int jB = (candB[0] == vB) ? 0                                   \
                     : (candB[1] == vB) ? 1                                   \
                     : (candB[2] == vB) ? 2 : 3;                              \
        Mb[0][WB][tid] = vA;                                                  \
        Mb[1][WB][tid] = vB;                                                  \
        const unsigned long long a0 = __ballot(jA & 1);                       \
        const unsigned long long a1 = __ballot(jA & 2);                       \
        const unsigned long long b0 = __ballot(jB & 1);                       \
        const unsigned long long b1 = __ballot(jB & 2);                       \
        if (lane == 0) {                                                      \
            ulonglong2 pa; pa.x = a0; pa.y = a1;                              \
            ulonglong2 pb; pb.x = b0; pb.y = b1;                              \
            J64[0][((T) << 2) | wid] = pa;                                    \
            J64[1][((T) << 2) | wid] = pb;                                    \
        }                                                                     \
        __syncthreads();                                                      \
    }

    // ---- forward recursion, t = 0..62 (31 pairs + 1), 1 barrier/step ----
    #pragma unroll 1
    for (int t = 0; t < 62; t += 2) {
        STEP2(t, 0, 1)
        STEP2(t + 1, 1, 0)
    }
    STEP2(62, 0, 1)
#undef STEP2

    // ---- final step t = 63: beta_63 for 4 states per chain, block argmax ----
    {
        const float4 xtA = *(const float4*)&tile[0][63 << 2];
        const float4 xtB = *(const float4*)&tile[1][63 << 2];
        float bvA = -3.4e38f, bvB = -3.4e38f;
        int   bsA = 0,        bsB = 0;
        #pragma unroll
        for (int j = 0; j < 4; ++j) {    // states ascend in j: first-max ok
            const float mA = Mb[0][1][(tid >> 2) + (j << 6)];
            const float mB = Mb[1][1][(tid >> 2) + (j << 6)];
            float accA = fmaf(a[j].x, xtA.x, h[j]);
            accA = fmaf(a[j].y, xtA.y, accA);
            accA = fmaf(a[j].z, xtA.z, accA);
            accA = fmaf(a[j].w, xtA.w, accA);
            accA += mA;
            if (accA > bvA) { bvA = accA; bsA = tid + (j << 8); }
            float accB = fmaf(a[j].x, xtB.x, h[j]);
            accB = fmaf(a[j].y, xtB.y, accB);
            accB = fmaf(a[j].z, xtB.z, accB);
            accB = fmaf(a[j].w, xtB.w, accB);
            accB += mB;
            if (accB > bvB) { bvB = accB; bsB = tid + (j << 8); }
        }
        // lexicographic (value desc, state asc) butterfly, chains interleaved
        #pragma unroll
        for (int off = 32; off > 0; off >>= 1) {
            const float ovA = __shfl_xor(bvA, off, 64);
            const int   osA = __shfl_xor(bsA, off, 64);
            const float ovB = __shfl_xor(bvB, off, 64);
            const int   osB = __shfl_xor(bsB, off, 64);
            if (ovA > bvA || (ovA == bvA && osA < bsA)) { bvA = ovA; bsA = osA; }
            if (ovB > bvB || (ovB == bvB && osB < bsB)) { bvB = ovB; bsB = osB; }
        }
        if (lane == 0) {
            redv[0][wid] = bvA; reds[0][wid] = bsA;
            redv[1][wid] = bvB; reds[1][wid] = bsB;
        }
    }
    __syncthreads();

    // ---- cross-wave combine + serial traceback: thread ch traces chain ch --
    if (tid < 2) {
        const int ch = tid;
        float gv = redv[ch][0];
        int   gs = reds[ch][0];
        #pragma unroll
        for (int w = 1; w < 4; ++w) {
            if (redv[ch][w] > gv || (redv[ch][w] == gv && reds[ch][w] < gs)) {
                gv = redv[ch][w];
                gs = reds[ch][w];
            }
        }
        int s = gs;
        st_lds[ch][T_STEPS - 1] = s;
        for (int i = T_STEPS - 2; i >= 0; --i) {
            const int p = s >> 2;
            const ulonglong2 bb = J64[ch][(i << 2) | (p >> 6)];
            const int l = p & 63;
            const int j = (int)((bb.x >> l) & 1ull) |
                          ((int)((bb.y >> l) & 1ull) << 1);
            s = p + (j << 8);
            st_lds[ch][i] = s;
        }
    }
    __syncthreads();

    // ---- outputs: threads 0..127, thread = (ch, t) ----
    if (tid < 128) {
        const int ch = tid >> 6;
        const int t  = tid & 63;
        const int chain = (blockIdx.x << 1) | ch;
        const int rb = chain >> 6, cb = chain & 63;
        const int st = st_lds[ch][t];
        // states_out flat: REC_SIZE + chain*64 + t   (stored as float values)
        out[REC_SIZE + chain * 64 + t] = (float)st;
        // rec: step t covers elements e = 4t..4t+3 -> row t>>2, cols 4*(t&3)..
        const float4 v = *(const float4*)(cbook + st * 4);
        const int r  = t >> 2;
        const int c4 = (t & 3) << 2;
        *(float4*)(out + (rb * 16 + r) * COLS + cb * 16 + c4) = v;
    }
}

extern "C" void kernel_launch(void* const* d_in, const int* in_sizes, int n_in,
                              void* d_out, int out_size, void* d_ws, size_t ws_size,
                              hipStream_t stream)
{
    const float* arr   = (const float*)d_in[0];
    const float* cbook = (const float*)d_in[1];
    float* out = (float*)d_out;
    // 4096 chains, 2 chains per 256-thread block -> 2048 blocks
    viterbi_q<<<dim3(2048), dim3(256), 0, stream>>>(arr, cbook, out);
}